// Round 17
// baseline (1045.448 us; speedup 1.0000x reference)
//
#include <hip/hip_runtime.h>

#define NN 100000
#define NE 640000
#define OUTF 128
#define K1 100
#define KE 118
#define KPAD 128
#define ASTR 136              // padded LDS row stride (ushorts) for node kernel
#define ATT_SCALE 0.17677669529663687f
#define NSCANB 391            // ceil(NN/256)
#define ETILES 5              // tiles per edge block (NE/64/2000)
#define ROWB 472              // EA row bytes (118 fp32)
#define WCHUNK 7552           // 16 rows * 472 B, per-wave stage chunk (16B-aligned: 16*472)
#define STAGEB (4 * WCHUNK)   // per buffer (4 waves) = 30208 B

typedef __attribute__((ext_vector_type(8))) short short8;
typedef __attribute__((ext_vector_type(4))) float f32x4;

__device__ __forceinline__ unsigned short f2bf(float f) {
    unsigned u = __float_as_uint(f);
    u += 0x7FFFu + ((u >> 16) & 1u);   // RNE
    return (unsigned short)(u >> 16);
}
__device__ __forceinline__ float bf2f(unsigned short h) {
    return __uint_as_float(((unsigned)h) << 16);
}
__device__ __forceinline__ void gld_lds16(const void* g, void* l) {
    __builtin_amdgcn_global_load_lds(
        (const __attribute__((address_space(1))) unsigned int*)g,
        (__attribute__((address_space(3))) unsigned int*)l, 16, 0, 0);
}

// ---------- prep: transposed bf16 weights [col][k]; WmT rows 118-121 = one-hot etype tables ----------
__global__ void prep_weights(
    const float* __restrict__ w1q, const float* __restrict__ w1k,
    const float* __restrict__ w1v, const float* __restrict__ w1s,
    const float* __restrict__ w2q, const float* __restrict__ w2k,
    const float* __restrict__ w2v, const float* __restrict__ w2s,
    const float* __restrict__ we1, const float* __restrict__ we2,
    const float* __restrict__ emb,
    const float* __restrict__ b1q, const float* __restrict__ b1k,
    const float* __restrict__ b1v, const float* __restrict__ b1s,
    const float* __restrict__ b2q, const float* __restrict__ b2k,
    const float* __restrict__ b2v, const float* __restrict__ b2s,
    unsigned short* __restrict__ WT1, unsigned short* __restrict__ WT2,
    unsigned short* __restrict__ WmT1, unsigned short* __restrict__ WmT2,
    float* __restrict__ bias1, float* __restrict__ bias2)
{
    int idx = blockIdx.x * blockDim.x + threadIdx.x;
    int stride = gridDim.x * blockDim.x;
    for (int i = idx; i < 512 * KPAD; i += stride) {
        int col = i >> 7, k = i & 127;
        int which = col >> 7, c = col & 127;
        const float* s1 = (which == 0) ? w1q : (which == 1) ? w1k : (which == 2) ? w1v : w1s;
        const float* s2 = (which == 0) ? w2q : (which == 1) ? w2k : (which == 2) ? w2v : w2s;
        float v1 = (k < K1) ? s1[k * OUTF + c] : 0.f;
        float v2 = s2[k * OUTF + c];
        WT1[i] = f2bf(v1); WT2[i] = f2bf(v2);
    }
    for (int i = idx; i < OUTF * KPAD; i += stride) {
        int col = i >> 7, k = i & 127;
        float v1 = 0.f, v2 = 0.f;
        if (k < 3)                 { v1 = we1[k * OUTF + col];       v2 = we2[k * OUTF + col]; }
        else if (k >= 4 && k < KE) { v1 = we1[(k - 1) * OUTF + col]; v2 = we2[(k - 1) * OUTF + col]; }
        else if (k >= KE && k < KE + 4) {
            int t = k - KE;
            #pragma unroll
            for (int r = 0; r < 8; r++) {
                float ev = emb[t * 8 + r];
                v1 += ev * we1[(117 + r) * OUTF + col];
                v2 += ev * we2[(117 + r) * OUTF + col];
            }
        }
        WmT1[i] = f2bf(v1); WmT2[i] = f2bf(v2);
    }
    for (int i = idx; i < 512; i += stride) {
        int which = i >> 7, c = i & 127;
        const float* sb1 = (which == 0) ? b1q : (which == 1) ? b1k : (which == 2) ? b1v : b1s;
        const float* sb2 = (which == 0) ? b2q : (which == 1) ? b2k : (which == 2) ? b2v : b2s;
        bias1[i] = sb1[c]; bias2[i] = sb2[c];
    }
}

// ---------- CSR build ----------
__global__ void hist_kernel(const int* __restrict__ dstI, int* __restrict__ cnt) {
    int e = blockIdx.x * 256 + threadIdx.x;
    if (e < NE) atomicAdd(&cnt[dstI[e]], 1);
}
__global__ void scan1(const int* __restrict__ cnt, int* __restrict__ S1, int* __restrict__ bsum) {
    __shared__ int sd[256];
    int t = blockIdx.x * 256 + threadIdx.x;
    sd[threadIdx.x] = (t < NN) ? cnt[t] : 0;
    __syncthreads();
    for (int off = 1; off < 256; off <<= 1) {
        int x = (threadIdx.x >= off) ? sd[threadIdx.x - off] : 0;
        __syncthreads();
        sd[threadIdx.x] += x;
        __syncthreads();
    }
    if (t < NN) S1[t] = sd[threadIdx.x];
    if (threadIdx.x == 255) bsum[blockIdx.x] = sd[255];
}
__global__ void scan2(const int* __restrict__ bsum, int* __restrict__ boff) {
    __shared__ int sd[512];
    int t = threadIdx.x;
    sd[t] = (t < NSCANB) ? bsum[t] : 0;
    __syncthreads();
    for (int off = 1; off < 512; off <<= 1) {
        int x = (t >= off) ? sd[t - off] : 0;
        __syncthreads();
        sd[t] += x;
        __syncthreads();
    }
    if (t < NSCANB) boff[t] = (t == 0) ? 0 : sd[t - 1];
}
__global__ void scan3(const int* __restrict__ S1, const int* __restrict__ boff,
                      const int* __restrict__ cnt,
                      int* __restrict__ row_start, int* __restrict__ cursor) {
    int t = blockIdx.x * 256 + threadIdx.x;
    if (t < NN) {
        int incl = S1[t] + boff[t >> 8];
        row_start[t + 1] = incl;
        cursor[t] = incl - cnt[t];
        if (t == 0) row_start[0] = 0;
    }
}
__global__ void scatter_csr(const int* __restrict__ srcI, const int* __restrict__ dstI,
                            int* __restrict__ cursor,
                            int* __restrict__ csr_src, int* __restrict__ csr_eid) {
    int e = blockIdx.x * 256 + threadIdx.x;
    if (e < NE) {
        int j = atomicAdd(&cursor[dstI[e]], 1);
        csr_src[j] = srcI[e];
        csr_eid[j] = e;
    }
}

// ---------- node GEMM, one 128-col block per block: coalesced LDS-staged epilogue ----------
__global__ __launch_bounds__(256) void node_mfma(
    const float* __restrict__ X, int ldx, int Kdim, int relu, int n,
    const unsigned short* __restrict__ WT, const float* __restrict__ bias,
    float* __restrict__ Qp, unsigned short* __restrict__ KVp, float* __restrict__ Hp)
{
    __shared__ unsigned short Alds[128][ASTR];     // A tile; reused as output staging after MFMA
    int tid = threadIdx.x;
    int rowbase = (blockIdx.x >> 2) * 128;
    int nb = blockIdx.x & 3;

    for (int idx = tid; idx < 128 * 68; idx += 256) {
        int r = idx / 68, kv = idx % 68;
        int k = kv * 2;
        float2 v = make_float2(0.f, 0.f);
        int gr = rowbase + r;
        if (gr < n && k < Kdim) v = *(const float2*)(X + (size_t)gr * ldx + k);
        if (relu) { v.x = fmaxf(v.x, 0.f); v.y = fmaxf(v.y, 0.f); }
        unsigned pv = (unsigned)f2bf(v.x) | ((unsigned)f2bf(v.y) << 16);
        *(unsigned*)&Alds[r][k] = pv;
    }
    __syncthreads();

    int lane = tid & 63, wid = tid >> 6;
    int wm = wid >> 1, wn = wid & 1;
    int l15 = lane & 15, l4 = lane >> 4;

    f32x4 acc[4][4];
    #pragma unroll
    for (int mf = 0; mf < 4; mf++)
        #pragma unroll
        for (int nf = 0; nf < 4; nf++)
            acc[mf][nf] = (f32x4){0.f, 0.f, 0.f, 0.f};

    const unsigned short* wbase = WT + (size_t)(nb * 128 + wn * 64 + l15) * KPAD + l4 * 8;
    #pragma unroll
    for (int ks = 0; ks < 4; ks++) {
        short8 af[4], bfr[4];
        #pragma unroll
        for (int mf = 0; mf < 4; mf++)
            af[mf] = *(const short8*)&Alds[wm * 64 + mf * 16 + l15][ks * 32 + l4 * 8];
        #pragma unroll
        for (int nf = 0; nf < 4; nf++)
            bfr[nf] = *(const short8*)(wbase + (size_t)nf * 16 * KPAD + ks * 32);
        #pragma unroll
        for (int mf = 0; mf < 4; mf++)
            #pragma unroll
            for (int nf = 0; nf < 4; nf++)
                acc[mf][nf] = __builtin_amdgcn_mfma_f32_16x16x32_bf16(af[mf], bfr[nf], acc[mf][nf], 0, 0, 0);
    }
    __syncthreads();   // A tile dead; reuse LDS for output staging

    if (nb == 1 || nb == 2) {
        #pragma unroll
        for (int nf = 0; nf < 4; nf++) {
            int col = wn * 64 + nf * 16 + l15;
            float bv = bias[nb * 128 + col];
            #pragma unroll
            for (int mf = 0; mf < 4; mf++)
                #pragma unroll
                for (int rr = 0; rr < 4; rr++)
                    Alds[wm * 64 + mf * 16 + l4 * 4 + rr][col] = f2bf(acc[mf][nf][rr] + bv);
        }
        __syncthreads();
        int off = (nb == 1) ? 0 : 128;
        #pragma unroll
        for (int it = 0; it < 8; it++) {
            int idx = it * 256 + tid;
            int row = idx >> 4, c8 = (idx & 15) * 8;
            if (rowbase + row < n) {
                uint4 v = *(const uint4*)&Alds[row][c8];
                *(uint4*)(KVp + (size_t)(rowbase + row) * 256 + off + c8) = v;
            }
        }
    } else {
        float* Yp = (nb == 0) ? Qp : Hp;
        float scale = (nb == 0) ? ATT_SCALE : 1.f;
        float (*Sf)[68] = (float (*)[68])Alds;
        #pragma unroll
        for (int h = 0; h < 2; h++) {
            if (wn == h) {
                #pragma unroll
                for (int nf = 0; nf < 4; nf++) {
                    int col = wn * 64 + nf * 16 + l15;
                    float bv = bias[nb * 128 + col];
                    #pragma unroll
                    for (int mf = 0; mf < 4; mf++)
                        #pragma unroll
                        for (int rr = 0; rr < 4; rr++)
                            Sf[wm * 64 + mf * 16 + l4 * 4 + rr][nf * 16 + l15] =
                                (acc[mf][nf][rr] + bv) * scale;
                }
            }
            __syncthreads();
            #pragma unroll
            for (int it = 0; it < 8; it++) {
                int idx = it * 256 + tid;
                int row = idx >> 4, c4 = (idx & 15) * 4;
                if (rowbase + row < n) {
                    float4 v = *(const float4*)&Sf[row][c4];
                    *(float4*)(Yp + (size_t)(rowbase + row) * OUTF + h * 64 + c4) = v;
                }
            }
            if (h == 0) __syncthreads();
        }
    }
}

// ---------- fused dual-layer edge GEMM: async global_load_lds double-buffer, zero barriers ----------
// Each wave's 16 EA rows are a contiguous 7552B chunk -> linear glds copy, wave-private.
// Counted vmcnt (never 0): stores + next prefetch stay in flight. Transpose reuses the stage chunk.
__global__ __launch_bounds__(256) void edge_mfma_fused(
    const float* __restrict__ EA,
    const unsigned short* __restrict__ WmT1, const unsigned short* __restrict__ WmT2,
    unsigned short* __restrict__ EE1, unsigned short* __restrict__ EE2)
{
    __shared__ char stage[2][STAGEB];
    int tid = threadIdx.x;
    int lane = tid & 63, w = tid >> 6;
    int l15 = lane & 15, l4 = lane >> 4;
    int tile0 = blockIdx.x * ETILES;

    char* wb0 = stage[0] + w * WCHUNK;
    char* wb1 = stage[1] + w * WCHUNK;
    const char* gEA = (const char*)EA;

    // linear async copy of this wave's 16 rows (7552B = 7 full 1KB instrs + 384B tail)
    auto issue_stage = [&](int tile, char* ldst) {
        const char* gsrc = gEA + (size_t)(tile * 64 + w * 16) * ROWB + lane * 16;
        #pragma unroll
        for (int i = 0; i < 7; i++)
            gld_lds16(gsrc + i * 1024, ldst + i * 1024);
        if (lane < 24)
            gld_lds16(gsrc + 7 * 1024, ldst + 7 * 1024);
    };
    // fragments from staged fp32 rows; convert to bf16; one-hot etype patch
    auto read_frag = [&](const char* wb, short8* af) {
        const float* rowp = (const float*)(wb + l15 * ROWB);
        float etf = rowp[3];
        #pragma unroll
        for (int ks = 0; ks < 4; ks++) {
            int cbase = ks * 32 + l4 * 8;
            float2 t0 = make_float2(0.f, 0.f), t1 = t0, t2 = t0, t3 = t0;
            if (cbase + 2 <= KE) t0 = *(const float2*)(rowp + cbase);
            if (cbase + 4 <= KE) t1 = *(const float2*)(rowp + cbase + 2);
            if (cbase + 6 <= KE) t2 = *(const float2*)(rowp + cbase + 4);
            if (cbase + 8 <= KE) t3 = *(const float2*)(rowp + cbase + 6);
            float fv[8] = {t0.x, t0.y, t1.x, t1.y, t2.x, t2.y, t3.x, t3.y};
            #pragma unroll
            for (int j = 0; j < 8; j++) {
                int col = cbase + j;
                float v = (col == 3) ? 0.f : fv[j];
                af[ks][j] = f2bf(v);
            }
        }
        int oh = KE + (int)etf;
        #pragma unroll
        for (int j = 0; j < 8; j++) {
            int col = 96 + l4 * 8 + j;
            if (col == oh) af[3][j] = 0x3F80;          // bf16 1.0
        }
    };
    auto do_layer = [&](const unsigned short* __restrict__ WmT, unsigned short* __restrict__ EEc,
                        int e0, const short8* af, char* wb) {
        f32x4 acc[8];
        #pragma unroll
        for (int nf = 0; nf < 8; nf++) acc[nf] = (f32x4){0.f, 0.f, 0.f, 0.f};

        #pragma unroll
        for (int ks = 0; ks < 4; ks++) {
            short8 bfr[8];
            #pragma unroll
            for (int nf = 0; nf < 8; nf++)
                bfr[nf] = *(const short8*)(WmT + (size_t)(nf * 16 + l15) * KPAD + ks * 32 + l4 * 8);
            #pragma unroll
            for (int nf = 0; nf < 8; nf++)
                acc[nf] = __builtin_amdgcn_mfma_f32_16x16x32_bf16(af[ks], bfr[nf], acc[nf], 0, 0, 0);
        }
        // transpose through the (now dead) stage chunk: 16 rows x 136 ushorts (272B, 16B-aligned)
        unsigned short* tb = (unsigned short*)wb;
        #pragma unroll
        for (int nf = 0; nf < 8; nf++)
            #pragma unroll
            for (int rr = 0; rr < 4; rr++)
                tb[(l4 * 4 + rr) * 136 + nf * 16 + l15] = f2bf(acc[nf][rr]);
        #pragma unroll
        for (int it = 0; it < 4; it++) {
            int t2 = it * 64 + lane;
            int rid = t2 >> 4, c8 = (t2 & 15) * 8;
            uint4 v = *(const uint4*)(tb + rid * 136 + c8);
            *(uint4*)(EEc + ((size_t)(e0 + w * 16 + rid)) * 128 + c8) = v;
        }
    };

    issue_stage(tile0, wb0);

    short8 afA[4];
    #pragma unroll
    for (int t = 0; t < ETILES; t++) {
        char* cur = (t & 1) ? wb1 : wb0;
        char* nxt = (t & 1) ? wb0 : wb1;
        if (t + 1 < ETILES) issue_stage(tile0 + t + 1, nxt);
        // wait for tile t's 8 glds; allow stores + next prefetch to stay outstanding
        if (t == 0 || t == ETILES - 1) asm volatile("s_waitcnt vmcnt(8)" ::: "memory");
        else                           asm volatile("s_waitcnt vmcnt(16)" ::: "memory");
        read_frag(cur, afA);
        int e0 = (tile0 + t) * 64;
        do_layer(WmT1, EE1, e0, afA, cur);
        do_layer(WmT2, EE2, e0, afA, cur);
    }
}

// ---------- fused attn: one wave per dst, online softmax, 3-deep data pipeline, zero atomics ----------
__global__ __launch_bounds__(256) void attn_node(
    const float* __restrict__ Qp, const unsigned short* __restrict__ KVp,
    const unsigned short* __restrict__ EEc,
    const int* __restrict__ row_start, const int* __restrict__ csr_src,
    const int* __restrict__ csr_eid,
    const float* __restrict__ Hskip, float* __restrict__ Out)
{
    int lane = threadIdx.x & 63;
    int gw = (int)((blockIdx.x * (size_t)blockDim.x + threadIdx.x) >> 6);
    int nW = (gridDim.x * blockDim.x) >> 6;
    int c2 = lane * 2;

    for (int d = gw; d < NN; d += nW) {
        int rs = row_start[d], re = row_start[d + 1];
        float2 q = *(const float2*)(Qp + (size_t)d * OUTF + c2);
        float m = -3.4e38f, s = 0.f, a0 = 0.f, a1 = 0.f;

        int j0 = (rs < re) ? rs : 0;
        int jlast = (rs < re) ? re - 1 : 0;
        int j1 = (j0 + 1 <= jlast) ? j0 + 1 : jlast;
        int j2 = (j0 + 2 <= jlast) ? j0 + 2 : jlast;
        int sjA = csr_src[j0], ejA = csr_eid[j0];
        int sjB = csr_src[j1], ejB = csr_eid[j1];
        int sjC = csr_src[j2], ejC = csr_eid[j2];
        unsigned kA = *(const unsigned*)(KVp + (size_t)sjA * 256 + c2);
        unsigned vA = *(const unsigned*)(KVp + (size_t)sjA * 256 + 128 + c2);
        unsigned eA = *(const unsigned*)(EEc + (size_t)ejA * 128 + c2);
        unsigned kB = *(const unsigned*)(KVp + (size_t)sjB * 256 + c2);
        unsigned vB = *(const unsigned*)(KVp + (size_t)sjB * 256 + 128 + c2);
        unsigned eB = *(const unsigned*)(EEc + (size_t)ejB * 128 + c2);

        for (int j = rs; j < re; j++) {
            unsigned kC = *(const unsigned*)(KVp + (size_t)sjC * 256 + c2);
            unsigned vC = *(const unsigned*)(KVp + (size_t)sjC * 256 + 128 + c2);
            unsigned eC = *(const unsigned*)(EEc + (size_t)ejC * 128 + c2);
            int j3 = (j + 3 <= jlast) ? j + 3 : jlast;
            int sjD = csr_src[j3], ejD = csr_eid[j3];

            float e0 = bf2f((unsigned short)(eA & 0xFFFFu));
            float e1 = bf2f((unsigned short)(eA >> 16));
            float k0 = bf2f((unsigned short)(kA & 0xFFFFu));
            float k1 = bf2f((unsigned short)(kA >> 16));
            float v0 = bf2f((unsigned short)(vA & 0xFFFFu));
            float v1 = bf2f((unsigned short)(vA >> 16));

            float t = q.x * (k0 + e0) + q.y * (k1 + e1);
            t += __shfl_xor(t, 1); t += __shfl_xor(t, 2);
            t += __shfl_xor(t, 4); t += __shfl_xor(t, 8);
            float alpha = t;   // ATT_SCALE pre-folded into Q
            float mn = fmaxf(m, alpha);
            float r = __expf(m - mn);
            float p = __expf(alpha - mn);
            s = s * r + p;
            a0 = a0 * r + p * (v0 + e0);
            a1 = a1 * r + p * (v1 + e1);
            m = mn;
            kA = kB; vA = vB; eA = eB;
            kB = kC; vB = vC; eB = eC;
            sjC = sjD; ejC = ejD;
        }
        float inv = 1.f / (s + 1e-16f);
        float2 h = *(const float2*)(Hskip + (size_t)d * OUTF + c2);
        float2 o;
        o.x = a0 * inv + h.x;
        o.y = a1 * inv + h.y;
        *(float2*)(Out + (size_t)d * OUTF + c2) = o;
    }
}

extern "C" void kernel_launch(void* const* d_in, const int* in_sizes, int n_in,
                              void* d_out, int out_size, void* d_ws, size_t ws_size,
                              hipStream_t stream) {
    const float* x    = (const float*)d_in[0];
    const int*   ei   = (const int*)d_in[1];
    const float* ea   = (const float*)d_in[2];
    const float* emb  = (const float*)d_in[3];
    const float* w1q  = (const float*)d_in[4];  const float* b1q = (const float*)d_in[5];
    const float* w1k  = (const float*)d_in[6];  const float* b1k = (const float*)d_in[7];
    const float* w1v  = (const float*)d_in[8];  const float* b1v = (const float*)d_in[9];
    const float* w1e  = (const float*)d_in[10];
    const float* w1s  = (const float*)d_in[11]; const float* b1s = (const float*)d_in[12];
    const float* w2q  = (const float*)d_in[13]; const float* b2q = (const float*)d_in[14];
    const float* w2k  = (const float*)d_in[15]; const float* b2k = (const float*)d_in[16];
    const float* w2v  = (const float*)d_in[17]; const float* b2v = (const float*)d_in[18];
    const float* w2e  = (const float*)d_in[19];
    const float* w2s  = (const float*)d_in[20]; const float* b2s = (const float*)d_in[21];

    const int* srcI = ei;
    const int* dstI = ei + NE;

    float* Q = (float*)d_ws;                                        // N x 128 f32 (pre-scaled)
    unsigned short* KV = (unsigned short*)(Q + (size_t)NN * OUTF);  // N x 256 bf16 [K|V]
    float* H = (float*)(KV + (size_t)NN * 256);                     // N x 128 f32
    unsigned short* EE1 = (unsigned short*)(H + (size_t)NN * OUTF); // E x 128 bf16
    unsigned short* EE2 = EE1 + (size_t)NE * 128;                   // E x 128 bf16
    int* csr_src   = (int*)(EE2 + (size_t)NE * 128);
    int* csr_eid   = csr_src + NE;
    int* row_start = csr_eid + NE;            // N+1
    int* cursor    = row_start + NN + 1;
    int* cnt       = cursor + NN;
    int* S1        = cnt + NN;
    int* bsum      = S1 + NN;
    int* boff      = bsum + NSCANB;
    unsigned short* WT1  = (unsigned short*)(boff + NSCANB + 1);
    unsigned short* WT2  = WT1 + 512 * KPAD;
    unsigned short* WmT1 = WT2 + 512 * KPAD;
    unsigned short* WmT2 = WmT1 + OUTF * KPAD;
    float* bias1 = (float*)(WmT2 + OUTF * KPAD);
    float* bias2 = bias1 + 512;

    prep_weights<<<128, 256, 0, stream>>>(w1q, w1k, w1v, w1s, w2q, w2k, w2v, w2s,
                                          w1e, w2e, emb,
                                          b1q, b1k, b1v, b1s, b2q, b2k, b2v, b2s,
                                          WT1, WT2, WmT1, WmT2, bias1, bias2);
    hipMemsetAsync(cnt, 0, (size_t)NN * sizeof(int), stream);
    hist_kernel<<<NE / 256, 256, 0, stream>>>(dstI, cnt);
    scan1<<<NSCANB, 256, 0, stream>>>(cnt, S1, bsum);
    scan2<<<1, 512, 0, stream>>>(bsum, boff);
    scan3<<<NSCANB, 256, 0, stream>>>(S1, boff, cnt, row_start, cursor);
    scatter_csr<<<NE / 256, 256, 0, stream>>>(srcI, dstI, cursor, csr_src, csr_eid);

    int ngrid = ((NN + 127) / 128) * 4;   // 782 row-tiles x 4 col-blocks = 3128
    int egrid = NE / (64 * ETILES);       // 2000

    // ---- node features L1 + fused dual-layer edge GEMM (async glds pipeline, barrier-free) ----
    node_mfma<<<ngrid, 256, 0, stream>>>(x, K1, K1, 0, NN, WT1, bias1, Q, KV, H);
    edge_mfma_fused<<<egrid, 256, 0, stream>>>(ea, WmT1, WmT2, EE1, EE2);
    attn_node<<<4096, 256, 0, stream>>>(Q, KV, EE1, row_start, csr_src, csr_eid, H, H);

    // ---- layer 2 ----
    node_mfma<<<ngrid, 256, 0, stream>>>(H, OUTF, OUTF, 1, NN, WT2, bias2, Q, KV, (float*)d_out);
    attn_node<<<4096, 256, 0, stream>>>(Q, KV, EE2, row_start, csr_src, csr_eid, (float*)d_out, (float*)d_out);
}

// Round 18
// 987.788 us; speedup vs baseline: 1.0584x; 1.0584x over previous
//
#include <hip/hip_runtime.h>

#define NN 100000
#define NE 640000
#define OUTF 128
#define K1 100
#define KE 118
#define KPAD 128
#define ASTR 136              // padded LDS row stride (ushorts)
#define ATT_SCALE 0.17677669529663687f
#define NSCANB 391            // ceil(NN/256)
#define ETILES 5              // tiles per edge block (NE/64/2000)

typedef __attribute__((ext_vector_type(8))) short short8;
typedef __attribute__((ext_vector_type(4))) float f32x4;

__device__ __forceinline__ unsigned short f2bf(float f) {
    unsigned u = __float_as_uint(f);
    u += 0x7FFFu + ((u >> 16) & 1u);   // RNE
    return (unsigned short)(u >> 16);
}
__device__ __forceinline__ float bf2f(unsigned short h) {
    return __uint_as_float(((unsigned)h) << 16);
}

// ---------- prep: transposed bf16 weights [col][k]; WmT rows 118-121 = one-hot etype tables ----------
__global__ void prep_weights(
    const float* __restrict__ w1q, const float* __restrict__ w1k,
    const float* __restrict__ w1v, const float* __restrict__ w1s,
    const float* __restrict__ w2q, const float* __restrict__ w2k,
    const float* __restrict__ w2v, const float* __restrict__ w2s,
    const float* __restrict__ we1, const float* __restrict__ we2,
    const float* __restrict__ emb,
    const float* __restrict__ b1q, const float* __restrict__ b1k,
    const float* __restrict__ b1v, const float* __restrict__ b1s,
    const float* __restrict__ b2q, const float* __restrict__ b2k,
    const float* __restrict__ b2v, const float* __restrict__ b2s,
    unsigned short* __restrict__ WT1, unsigned short* __restrict__ WT2,
    unsigned short* __restrict__ WmT1, unsigned short* __restrict__ WmT2,
    float* __restrict__ bias1, float* __restrict__ bias2)
{
    int idx = blockIdx.x * blockDim.x + threadIdx.x;
    int stride = gridDim.x * blockDim.x;
    for (int i = idx; i < 512 * KPAD; i += stride) {
        int col = i >> 7, k = i & 127;
        int which = col >> 7, c = col & 127;
        const float* s1 = (which == 0) ? w1q : (which == 1) ? w1k : (which == 2) ? w1v : w1s;
        const float* s2 = (which == 0) ? w2q : (which == 1) ? w2k : (which == 2) ? w2v : w2s;
        float v1 = (k < K1) ? s1[k * OUTF + c] : 0.f;
        float v2 = s2[k * OUTF + c];
        WT1[i] = f2bf(v1); WT2[i] = f2bf(v2);
    }
    for (int i = idx; i < OUTF * KPAD; i += stride) {
        int col = i >> 7, k = i & 127;
        float v1 = 0.f, v2 = 0.f;
        if (k < 3)                 { v1 = we1[k * OUTF + col];       v2 = we2[k * OUTF + col]; }
        else if (k >= 4 && k < KE) { v1 = we1[(k - 1) * OUTF + col]; v2 = we2[(k - 1) * OUTF + col]; }
        else if (k >= KE && k < KE + 4) {
            int t = k - KE;
            #pragma unroll
            for (int r = 0; r < 8; r++) {
                float ev = emb[t * 8 + r];
                v1 += ev * we1[(117 + r) * OUTF + col];
                v2 += ev * we2[(117 + r) * OUTF + col];
            }
        }
        WmT1[i] = f2bf(v1); WmT2[i] = f2bf(v2);
    }
    for (int i = idx; i < 512; i += stride) {
        int which = i >> 7, c = i & 127;
        const float* sb1 = (which == 0) ? b1q : (which == 1) ? b1k : (which == 2) ? b1v : b1s;
        const float* sb2 = (which == 0) ? b2q : (which == 1) ? b2k : (which == 2) ? b2v : b2s;
        bias1[i] = sb1[c]; bias2[i] = sb2[c];
    }
}

// ---------- CSR build ----------
__global__ void hist_kernel(const int* __restrict__ dstI, int* __restrict__ cnt) {
    int e = blockIdx.x * 256 + threadIdx.x;
    if (e < NE) atomicAdd(&cnt[dstI[e]], 1);
}
__global__ void scan1(const int* __restrict__ cnt, int* __restrict__ S1, int* __restrict__ bsum) {
    __shared__ int sd[256];
    int t = blockIdx.x * 256 + threadIdx.x;
    sd[threadIdx.x] = (t < NN) ? cnt[t] : 0;
    __syncthreads();
    for (int off = 1; off < 256; off <<= 1) {
        int x = (threadIdx.x >= off) ? sd[threadIdx.x - off] : 0;
        __syncthreads();
        sd[threadIdx.x] += x;
        __syncthreads();
    }
    if (t < NN) S1[t] = sd[threadIdx.x];
    if (threadIdx.x == 255) bsum[blockIdx.x] = sd[255];
}
__global__ void scan2(const int* __restrict__ bsum, int* __restrict__ boff) {
    __shared__ int sd[512];
    int t = threadIdx.x;
    sd[t] = (t < NSCANB) ? bsum[t] : 0;
    __syncthreads();
    for (int off = 1; off < 512; off <<= 1) {
        int x = (t >= off) ? sd[t - off] : 0;
        __syncthreads();
        sd[t] += x;
        __syncthreads();
    }
    if (t < NSCANB) boff[t] = (t == 0) ? 0 : sd[t - 1];
}
__global__ void scan3(const int* __restrict__ S1, const int* __restrict__ boff,
                      const int* __restrict__ cnt,
                      int* __restrict__ row_start, int* __restrict__ cursor) {
    int t = blockIdx.x * 256 + threadIdx.x;
    if (t < NN) {
        int incl = S1[t] + boff[t >> 8];
        row_start[t + 1] = incl;
        cursor[t] = incl - cnt[t];
        if (t == 0) row_start[0] = 0;
    }
}
__global__ void scatter_csr(const int* __restrict__ srcI, const int* __restrict__ dstI,
                            int* __restrict__ cursor,
                            int* __restrict__ csr_src, int* __restrict__ csr_eid) {
    int e = blockIdx.x * 256 + threadIdx.x;
    if (e < NE) {
        int j = atomicAdd(&cursor[dstI[e]], 1);
        csr_src[j] = srcI[e];
        csr_eid[j] = e;
    }
}

// ---------- node GEMM, one 128-col block per block: coalesced LDS-staged epilogue ----------
// grid = ngrid*4; blockIdx = rowtile*4 + nb. nb: 0=Q(f32, pre-scaled) 1=K(bf16) 2=V(bf16) 3=H(f32)
__global__ __launch_bounds__(256) void node_mfma(
    const float* __restrict__ X, int ldx, int Kdim, int relu, int n,
    const unsigned short* __restrict__ WT, const float* __restrict__ bias,
    float* __restrict__ Qp, unsigned short* __restrict__ KVp, float* __restrict__ Hp)
{
    __shared__ unsigned short Alds[128][ASTR];     // A tile; reused as output staging after MFMA
    int tid = threadIdx.x;
    int rowbase = (blockIdx.x >> 2) * 128;
    int nb = blockIdx.x & 3;

    for (int idx = tid; idx < 128 * 68; idx += 256) {
        int r = idx / 68, kv = idx % 68;
        int k = kv * 2;
        float2 v = make_float2(0.f, 0.f);
        int gr = rowbase + r;
        if (gr < n && k < Kdim) v = *(const float2*)(X + (size_t)gr * ldx + k);
        if (relu) { v.x = fmaxf(v.x, 0.f); v.y = fmaxf(v.y, 0.f); }
        unsigned pv = (unsigned)f2bf(v.x) | ((unsigned)f2bf(v.y) << 16);
        *(unsigned*)&Alds[r][k] = pv;
    }
    __syncthreads();

    int lane = tid & 63, wid = tid >> 6;
    int wm = wid >> 1, wn = wid & 1;
    int l15 = lane & 15, l4 = lane >> 4;

    f32x4 acc[4][4];
    #pragma unroll
    for (int mf = 0; mf < 4; mf++)
        #pragma unroll
        for (int nf = 0; nf < 4; nf++)
            acc[mf][nf] = (f32x4){0.f, 0.f, 0.f, 0.f};

    const unsigned short* wbase = WT + (size_t)(nb * 128 + wn * 64 + l15) * KPAD + l4 * 8;
    #pragma unroll
    for (int ks = 0; ks < 4; ks++) {
        short8 af[4], bfr[4];
        #pragma unroll
        for (int mf = 0; mf < 4; mf++)
            af[mf] = *(const short8*)&Alds[wm * 64 + mf * 16 + l15][ks * 32 + l4 * 8];
        #pragma unroll
        for (int nf = 0; nf < 4; nf++)
            bfr[nf] = *(const short8*)(wbase + (size_t)nf * 16 * KPAD + ks * 32);
        #pragma unroll
        for (int mf = 0; mf < 4; mf++)
            #pragma unroll
            for (int nf = 0; nf < 4; nf++)
                acc[mf][nf] = __builtin_amdgcn_mfma_f32_16x16x32_bf16(af[mf], bfr[nf], acc[mf][nf], 0, 0, 0);
    }
    __syncthreads();   // A tile dead; reuse LDS for output staging

    if (nb == 1 || nb == 2) {
        // --- bf16 K/V: one 128x128 ushort tile, uint4 stores (full 256B rows) ---
        #pragma unroll
        for (int nf = 0; nf < 4; nf++) {
            int col = wn * 64 + nf * 16 + l15;
            float bv = bias[nb * 128 + col];
            #pragma unroll
            for (int mf = 0; mf < 4; mf++)
                #pragma unroll
                for (int rr = 0; rr < 4; rr++)
                    Alds[wm * 64 + mf * 16 + l4 * 4 + rr][col] = f2bf(acc[mf][nf][rr] + bv);
        }
        __syncthreads();
        int off = (nb == 1) ? 0 : 128;
        #pragma unroll
        for (int it = 0; it < 8; it++) {
            int idx = it * 256 + tid;
            int row = idx >> 4, c8 = (idx & 15) * 8;
            if (rowbase + row < n) {
                uint4 v = *(const uint4*)&Alds[row][c8];
                *(uint4*)(KVp + (size_t)(rowbase + row) * 256 + off + c8) = v;
            }
        }
    } else {
        // --- f32 Q/H: two 64-col half tiles ([128][68] f32 == Alds footprint), float4 stores ---
        float* Yp = (nb == 0) ? Qp : Hp;
        float scale = (nb == 0) ? ATT_SCALE : 1.f;
        float (*Sf)[68] = (float (*)[68])Alds;
        #pragma unroll
        for (int h = 0; h < 2; h++) {
            if (wn == h) {
                #pragma unroll
                for (int nf = 0; nf < 4; nf++) {
                    int col = wn * 64 + nf * 16 + l15;
                    float bv = bias[nb * 128 + col];
                    #pragma unroll
                    for (int mf = 0; mf < 4; mf++)
                        #pragma unroll
                        for (int rr = 0; rr < 4; rr++)
                            Sf[wm * 64 + mf * 16 + l4 * 4 + rr][nf * 16 + l15] =
                                (acc[mf][nf][rr] + bv) * scale;
                }
            }
            __syncthreads();
            #pragma unroll
            for (int it = 0; it < 8; it++) {
                int idx = it * 256 + tid;
                int row = idx >> 4, c4 = (idx & 15) * 4;
                if (rowbase + row < n) {
                    float4 v = *(const float4*)&Sf[row][c4];
                    *(float4*)(Yp + (size_t)(rowbase + row) * OUTF + h * 64 + c4) = v;
                }
            }
            if (h == 0) __syncthreads();
        }
    }
}

// ---------- fused dual-layer edge GEMM: 5 tiles/block, reg prefetch (R15-proven) + setprio ----------
// Zero barriers. Only the bf16 fragment path; prefetch of tile t+1 in flight under layer 2.
__global__ __launch_bounds__(256) void edge_mfma_fused(
    const float* __restrict__ EA,
    const unsigned short* __restrict__ WmT1, const unsigned short* __restrict__ WmT2,
    unsigned short* __restrict__ EE1, unsigned short* __restrict__ EE2)
{
    __shared__ unsigned short Tlds[64][ASTR];   // transpose buffer (wave-private quadrants)
    int tid = threadIdx.x;
    int lane = tid & 63, w = tid >> 6;
    int l15 = lane & 15, l4 = lane >> 4;
    int rbase = w * 16;
    int tile0 = blockIdx.x * ETILES;

    // load a tile's fragment, converting fp32 -> bf16 (raw fp32 temps live until converted)
    auto load_tile = [&](int tile, short8* af) {
        const float* rp = EA + (size_t)(tile * 64 + rbase + l15) * KE;
        float etf = rp[3];
        #pragma unroll
        for (int ks = 0; ks < 4; ks++) {
            int cbase = ks * 32 + l4 * 8;
            float2 t0 = make_float2(0.f, 0.f), t1 = t0, t2 = t0, t3 = t0;
            if (cbase + 2 <= KE) t0 = *(const float2*)(rp + cbase);
            if (cbase + 4 <= KE) t1 = *(const float2*)(rp + cbase + 2);
            if (cbase + 6 <= KE) t2 = *(const float2*)(rp + cbase + 4);
            if (cbase + 8 <= KE) t3 = *(const float2*)(rp + cbase + 6);
            float fv[8] = {t0.x, t0.y, t1.x, t1.y, t2.x, t2.y, t3.x, t3.y};
            #pragma unroll
            for (int j = 0; j < 8; j++) {
                int col = cbase + j;
                float v = (col == 3) ? 0.f : fv[j];    // col 3 = etype -> zero
                af[ks][j] = f2bf(v);
            }
        }
        int oh = KE + (int)etf;                        // one-hot col 118..121 (ks==3 chunk)
        #pragma unroll
        for (int j = 0; j < 8; j++) {
            int col = 96 + l4 * 8 + j;
            if (col == oh) af[3][j] = 0x3F80;          // bf16 1.0
        }
    };
    auto do_layer = [&](const unsigned short* __restrict__ WmT, unsigned short* __restrict__ EEc,
                        int e0, const short8* af) {
        f32x4 acc[8];
        #pragma unroll
        for (int nf = 0; nf < 8; nf++) acc[nf] = (f32x4){0.f, 0.f, 0.f, 0.f};

        __builtin_amdgcn_s_setprio(1);
        #pragma unroll
        for (int ks = 0; ks < 4; ks++) {
            short8 bfr[8];
            #pragma unroll
            for (int nf = 0; nf < 8; nf++)
                bfr[nf] = *(const short8*)(WmT + (size_t)(nf * 16 + l15) * KPAD + ks * 32 + l4 * 8);
            #pragma unroll
            for (int nf = 0; nf < 8; nf++)
                acc[nf] = __builtin_amdgcn_mfma_f32_16x16x32_bf16(af[ks], bfr[nf], acc[nf], 0, 0, 0);
        }
        __builtin_amdgcn_s_setprio(0);
        // wave-private transpose through own LDS rows (no barrier), coalesced linear store
        #pragma unroll
        for (int nf = 0; nf < 8; nf++)
            #pragma unroll
            for (int rr = 0; rr < 4; rr++)
                Tlds[rbase + l4 * 4 + rr][nf * 16 + l15] = f2bf(acc[nf][rr]);
        #pragma unroll
        for (int it = 0; it < 4; it++) {
            int t2 = it * 64 + lane;
            int rid = t2 >> 4, c8 = (t2 & 15) * 8;     // rid spans [0,16) over it=0..3
            uint4 v = *(const uint4*)&Tlds[rbase + rid][c8];
            *(uint4*)(EEc + ((size_t)(e0 + rbase + rid)) * 128 + c8) = v;
        }
    };

    short8 afA[4];
    load_tile(tile0, afA);

    #pragma unroll
    for (int t = 0; t < ETILES; t++) {
        int e0 = (tile0 + t) * 64;
        do_layer(WmT1, EE1, e0, afA);
        short8 afB[4];
        if (t + 1 < ETILES) load_tile(tile0 + t + 1, afB);   // loads in flight under layer 2
        do_layer(WmT2, EE2, e0, afA);
        if (t + 1 < ETILES) {
            afA[0] = afB[0]; afA[1] = afB[1]; afA[2] = afB[2]; afA[3] = afB[3];
        }
    }
}

// ---------- fused attn: one wave per dst, online softmax, 3-deep data pipeline, zero atomics ----------
__global__ __launch_bounds__(256) void attn_node(
    const float* __restrict__ Qp, const unsigned short* __restrict__ KVp,
    const unsigned short* __restrict__ EEc,
    const int* __restrict__ row_start, const int* __restrict__ csr_src,
    const int* __restrict__ csr_eid,
    const float* __restrict__ Hskip, float* __restrict__ Out)
{
    int lane = threadIdx.x & 63;
    int gw = (int)((blockIdx.x * (size_t)blockDim.x + threadIdx.x) >> 6);
    int nW = (gridDim.x * blockDim.x) >> 6;
    int c2 = lane * 2;

    for (int d = gw; d < NN; d += nW) {
        int rs = row_start[d], re = row_start[d + 1];
        float2 q = *(const float2*)(Qp + (size_t)d * OUTF + c2);
        float m = -3.4e38f, s = 0.f, a0 = 0.f, a1 = 0.f;

        int j0 = (rs < re) ? rs : 0;
        int jlast = (rs < re) ? re - 1 : 0;
        int j1 = (j0 + 1 <= jlast) ? j0 + 1 : jlast;
        int j2 = (j0 + 2 <= jlast) ? j0 + 2 : jlast;
        int sjA = csr_src[j0], ejA = csr_eid[j0];
        int sjB = csr_src[j1], ejB = csr_eid[j1];
        int sjC = csr_src[j2], ejC = csr_eid[j2];
        unsigned kA = *(const unsigned*)(KVp + (size_t)sjA * 256 + c2);
        unsigned vA = *(const unsigned*)(KVp + (size_t)sjA * 256 + 128 + c2);
        unsigned eA = *(const unsigned*)(EEc + (size_t)ejA * 128 + c2);
        unsigned kB = *(const unsigned*)(KVp + (size_t)sjB * 256 + c2);
        unsigned vB = *(const unsigned*)(KVp + (size_t)sjB * 256 + 128 + c2);
        unsigned eB = *(const unsigned*)(EEc + (size_t)ejB * 128 + c2);

        for (int j = rs; j < re; j++) {
            unsigned kC = *(const unsigned*)(KVp + (size_t)sjC * 256 + c2);
            unsigned vC = *(const unsigned*)(KVp + (size_t)sjC * 256 + 128 + c2);
            unsigned eC = *(const unsigned*)(EEc + (size_t)ejC * 128 + c2);
            int j3 = (j + 3 <= jlast) ? j + 3 : jlast;
            int sjD = csr_src[j3], ejD = csr_eid[j3];

            float e0 = bf2f((unsigned short)(eA & 0xFFFFu));
            float e1 = bf2f((unsigned short)(eA >> 16));
            float k0 = bf2f((unsigned short)(kA & 0xFFFFu));
            float k1 = bf2f((unsigned short)(kA >> 16));
            float v0 = bf2f((unsigned short)(vA & 0xFFFFu));
            float v1 = bf2f((unsigned short)(vA >> 16));

            float t = q.x * (k0 + e0) + q.y * (k1 + e1);
            t += __shfl_xor(t, 1); t += __shfl_xor(t, 2);
            t += __shfl_xor(t, 4); t += __shfl_xor(t, 8);
            float alpha = t;   // ATT_SCALE pre-folded into Q
            float mn = fmaxf(m, alpha);
            float r = __expf(m - mn);
            float p = __expf(alpha - mn);
            s = s * r + p;
            a0 = a0 * r + p * (v0 + e0);
            a1 = a1 * r + p * (v1 + e1);
            m = mn;
            kA = kB; vA = vB; eA = eB;
            kB = kC; vB = vC; eB = eC;
            sjC = sjD; ejC = ejD;
        }
        float inv = 1.f / (s + 1e-16f);
        float2 h = *(const float2*)(Hskip + (size_t)d * OUTF + c2);
        float2 o;
        o.x = a0 * inv + h.x;
        o.y = a1 * inv + h.y;
        *(float2*)(Out + (size_t)d * OUTF + c2) = o;
    }
}

extern "C" void kernel_launch(void* const* d_in, const int* in_sizes, int n_in,
                              void* d_out, int out_size, void* d_ws, size_t ws_size,
                              hipStream_t stream) {
    const float* x    = (const float*)d_in[0];
    const int*   ei   = (const int*)d_in[1];
    const float* ea   = (const float*)d_in[2];
    const float* emb  = (const float*)d_in[3];
    const float* w1q  = (const float*)d_in[4];  const float* b1q = (const float*)d_in[5];
    const float* w1k  = (const float*)d_in[6];  const float* b1k = (const float*)d_in[7];
    const float* w1v  = (const float*)d_in[8];  const float* b1v = (const float*)d_in[9];
    const float* w1e  = (const float*)d_in[10];
    const float* w1s  = (const float*)d_in[11]; const float* b1s = (const float*)d_in[12];
    const float* w2q  = (const float*)d_in[13]; const float* b2q = (const float*)d_in[14];
    const float* w2k  = (const float*)d_in[15]; const float* b2k = (const float*)d_in[16];
    const float* w2v  = (const float*)d_in[17]; const float* b2v = (const float*)d_in[18];
    const float* w2e  = (const float*)d_in[19];
    const float* w2s  = (const float*)d_in[20]; const float* b2s = (const float*)d_in[21];

    const int* srcI = ei;
    const int* dstI = ei + NE;

    float* Q = (float*)d_ws;                                        // N x 128 f32 (pre-scaled)
    unsigned short* KV = (unsigned short*)(Q + (size_t)NN * OUTF);  // N x 256 bf16 [K|V]
    float* H = (float*)(KV + (size_t)NN * 256);                     // N x 128 f32
    unsigned short* EE1 = (unsigned short*)(H + (size_t)NN * OUTF); // E x 128 bf16
    unsigned short* EE2 = EE1 + (size_t)NE * 128;                   // E x 128 bf16
    int* csr_src   = (int*)(EE2 + (size_t)NE * 128);
    int* csr_eid   = csr_src + NE;
    int* row_start = csr_eid + NE;            // N+1
    int* cursor    = row_start + NN + 1;
    int* cnt       = cursor + NN;
    int* S1        = cnt + NN;
    int* bsum      = S1 + NN;
    int* boff      = bsum + NSCANB;
    unsigned short* WT1  = (unsigned short*)(boff + NSCANB + 1);
    unsigned short* WT2  = WT1 + 512 * KPAD;
    unsigned short* WmT1 = WT2 + 512 * KPAD;
    unsigned short* WmT2 = WmT1 + OUTF * KPAD;
    float* bias1 = (float*)(WmT2 + OUTF * KPAD);
    float* bias2 = bias1 + 512;

    prep_weights<<<128, 256, 0, stream>>>(w1q, w1k, w1v, w1s, w2q, w2k, w2v, w2s,
                                          w1e, w2e, emb,
                                          b1q, b1k, b1v, b1s, b2q, b2k, b2v, b2s,
                                          WT1, WT2, WmT1, WmT2, bias1, bias2);
    hipMemsetAsync(cnt, 0, (size_t)NN * sizeof(int), stream);
    hist_kernel<<<NE / 256, 256, 0, stream>>>(dstI, cnt);
    scan1<<<NSCANB, 256, 0, stream>>>(cnt, S1, bsum);
    scan2<<<1, 512, 0, stream>>>(bsum, boff);
    scan3<<<NSCANB, 256, 0, stream>>>(S1, boff, cnt, row_start, cursor);
    scatter_csr<<<NE / 256, 256, 0, stream>>>(srcI, dstI, cursor, csr_src, csr_eid);

    int ngrid = ((NN + 127) / 128) * 4;   // 782 row-tiles x 4 col-blocks = 3128
    int egrid = NE / (64 * ETILES);       // 2000

    // ---- node features L1 + fused dual-layer edge GEMM (pipelined, barrier-free) ----
    node_mfma<<<ngrid, 256, 0, stream>>>(x, K1, K1, 0, NN, WT1, bias1, Q, KV, H);
    edge_mfma_fused<<<egrid, 256, 0, stream>>>(ea, WmT1, WmT2, EE1, EE2);
    attn_node<<<4096, 256, 0, stream>>>(Q, KV, EE1, row_start, csr_src, csr_eid, H, H);

    // ---- layer 2 ----
    node_mfma<<<ngrid, 256, 0, stream>>>(H, OUTF, OUTF, 1, NN, WT2, bias2, Q, KV, (float*)d_out);
    attn_node<<<4096, 256, 0, stream>>>(Q, KV, EE2, row_start, csr_src, csr_eid, (float*)d_out, (float*)d_out);
}

// Round 20
// 977.420 us; speedup vs baseline: 1.0696x; 1.0106x over previous
//
#include <hip/hip_runtime.h>

#define NN 100000
#define NE 640000
#define OUTF 128
#define K1 100
#define KE 118
#define KPAD 128
#define ASTR 136              // padded LDS row stride (ushorts)
#define ATT_SCALE 0.17677669529663687f
#define NSCANB 391            // ceil(NN/256)
#define ETILES 5              // tiles per edge block (NE/64/2000)

typedef __attribute__((ext_vector_type(8))) short short8;
typedef __attribute__((ext_vector_type(4))) float f32x4;

__device__ __forceinline__ unsigned short f2bf(float f) {
    unsigned u = __float_as_uint(f);
    u += 0x7FFFu + ((u >> 16) & 1u);   // RNE
    return (unsigned short)(u >> 16);
}
__device__ __forceinline__ float bf2f(unsigned short h) {
    return __uint_as_float(((unsigned)h) << 16);
}

// ---------- prep: transposed bf16 weights [col][k]; WmT rows 118-121 = one-hot etype tables ----------
__global__ void prep_weights(
    const float* __restrict__ w1q, const float* __restrict__ w1k,
    const float* __restrict__ w1v, const float* __restrict__ w1s,
    const float* __restrict__ w2q, const float* __restrict__ w2k,
    const float* __restrict__ w2v, const float* __restrict__ w2s,
    const float* __restrict__ we1, const float* __restrict__ we2,
    const float* __restrict__ emb,
    const float* __restrict__ b1q, const float* __restrict__ b1k,
    const float* __restrict__ b1v, const float* __restrict__ b1s,
    const float* __restrict__ b2q, const float* __restrict__ b2k,
    const float* __restrict__ b2v, const float* __restrict__ b2s,
    unsigned short* __restrict__ WT1, unsigned short* __restrict__ WT2,
    unsigned short* __restrict__ WmT1, unsigned short* __restrict__ WmT2,
    float* __restrict__ bias1, float* __restrict__ bias2)
{
    int idx = blockIdx.x * blockDim.x + threadIdx.x;
    int stride = gridDim.x * blockDim.x;
    for (int i = idx; i < 512 * KPAD; i += stride) {
        int col = i >> 7, k = i & 127;
        int which = col >> 7, c = col & 127;
        const float* s1 = (which == 0) ? w1q : (which == 1) ? w1k : (which == 2) ? w1v : w1s;
        const float* s2 = (which == 0) ? w2q : (which == 1) ? w2k : (which == 2) ? w2v : w2s;
        float v1 = (k < K1) ? s1[k * OUTF + c] : 0.f;
        float v2 = s2[k * OUTF + c];
        WT1[i] = f2bf(v1); WT2[i] = f2bf(v2);
    }
    for (int i = idx; i < OUTF * KPAD; i += stride) {
        int col = i >> 7, k = i & 127;
        float v1 = 0.f, v2 = 0.f;
        if (k < 3)                 { v1 = we1[k * OUTF + col];       v2 = we2[k * OUTF + col]; }
        else if (k >= 4 && k < KE) { v1 = we1[(k - 1) * OUTF + col]; v2 = we2[(k - 1) * OUTF + col]; }
        else if (k >= KE && k < KE + 4) {
            int t = k - KE;
            #pragma unroll
            for (int r = 0; r < 8; r++) {
                float ev = emb[t * 8 + r];
                v1 += ev * we1[(117 + r) * OUTF + col];
                v2 += ev * we2[(117 + r) * OUTF + col];
            }
        }
        WmT1[i] = f2bf(v1); WmT2[i] = f2bf(v2);
    }
    for (int i = idx; i < 512; i += stride) {
        int which = i >> 7, c = i & 127;
        const float* sb1 = (which == 0) ? b1q : (which == 1) ? b1k : (which == 2) ? b1v : b1s;
        const float* sb2 = (which == 0) ? b2q : (which == 1) ? b2k : (which == 2) ? b2v : b2s;
        bias1[i] = sb1[c]; bias2[i] = sb2[c];
    }
}

// ---------- CSR build ----------
__global__ void hist_kernel(const int* __restrict__ dstI, int* __restrict__ cnt) {
    int e = blockIdx.x * 256 + threadIdx.x;
    if (e < NE) atomicAdd(&cnt[dstI[e]], 1);
}
__global__ void scan1(const int* __restrict__ cnt, int* __restrict__ S1, int* __restrict__ bsum) {
    __shared__ int sd[256];
    int t = blockIdx.x * 256 + threadIdx.x;
    sd[threadIdx.x] = (t < NN) ? cnt[t] : 0;
    __syncthreads();
    for (int off = 1; off < 256; off <<= 1) {
        int x = (threadIdx.x >= off) ? sd[threadIdx.x - off] : 0;
        __syncthreads();
        sd[threadIdx.x] += x;
        __syncthreads();
    }
    if (t < NN) S1[t] = sd[threadIdx.x];
    if (threadIdx.x == 255) bsum[blockIdx.x] = sd[255];
}
__global__ void scan2(const int* __restrict__ bsum, int* __restrict__ boff) {
    __shared__ int sd[512];
    int t = threadIdx.x;
    sd[t] = (t < NSCANB) ? bsum[t] : 0;
    __syncthreads();
    for (int off = 1; off < 512; off <<= 1) {
        int x = (t >= off) ? sd[t - off] : 0;
        __syncthreads();
        sd[t] += x;
        __syncthreads();
    }
    if (t < NSCANB) boff[t] = (t == 0) ? 0 : sd[t - 1];
}
__global__ void scan3(const int* __restrict__ S1, const int* __restrict__ boff,
                      const int* __restrict__ cnt,
                      int* __restrict__ row_start, int* __restrict__ cursor) {
    int t = blockIdx.x * 256 + threadIdx.x;
    if (t < NN) {
        int incl = S1[t] + boff[t >> 8];
        row_start[t + 1] = incl;
        cursor[t] = incl - cnt[t];
        if (t == 0) row_start[0] = 0;
    }
}
__global__ void scatter_csr(const int* __restrict__ srcI, const int* __restrict__ dstI,
                            int* __restrict__ cursor, int2* __restrict__ csr_pair) {
    int e = blockIdx.x * 256 + threadIdx.x;
    if (e < NE) {
        int j = atomicAdd(&cursor[dstI[e]], 1);
        csr_pair[j] = make_int2(srcI[e], e);
    }
}

// ---------- node GEMM, one 128-col block per block: coalesced LDS-staged epilogue ----------
__global__ __launch_bounds__(256) void node_mfma(
    const float* __restrict__ X, int ldx, int Kdim, int relu, int n,
    const unsigned short* __restrict__ WT, const float* __restrict__ bias,
    float* __restrict__ Qp, unsigned short* __restrict__ KVp, float* __restrict__ Hp)
{
    __shared__ unsigned short Alds[128][ASTR];     // A tile; reused as output staging after MFMA
    int tid = threadIdx.x;
    int rowbase = (blockIdx.x >> 2) * 128;
    int nb = blockIdx.x & 3;

    for (int idx = tid; idx < 128 * 68; idx += 256) {
        int r = idx / 68, kv = idx % 68;
        int k = kv * 2;
        float2 v = make_float2(0.f, 0.f);
        int gr = rowbase + r;
        if (gr < n && k < Kdim) v = *(const float2*)(X + (size_t)gr * ldx + k);
        if (relu) { v.x = fmaxf(v.x, 0.f); v.y = fmaxf(v.y, 0.f); }
        unsigned pv = (unsigned)f2bf(v.x) | ((unsigned)f2bf(v.y) << 16);
        *(unsigned*)&Alds[r][k] = pv;
    }
    __syncthreads();

    int lane = tid & 63, wid = tid >> 6;
    int wm = wid >> 1, wn = wid & 1;
    int l15 = lane & 15, l4 = lane >> 4;

    f32x4 acc[4][4];
    #pragma unroll
    for (int mf = 0; mf < 4; mf++)
        #pragma unroll
        for (int nf = 0; nf < 4; nf++)
            acc[mf][nf] = (f32x4){0.f, 0.f, 0.f, 0.f};

    const unsigned short* wbase = WT + (size_t)(nb * 128 + wn * 64 + l15) * KPAD + l4 * 8;
    #pragma unroll
    for (int ks = 0; ks < 4; ks++) {
        short8 af[4], bfr[4];
        #pragma unroll
        for (int mf = 0; mf < 4; mf++)
            af[mf] = *(const short8*)&Alds[wm * 64 + mf * 16 + l15][ks * 32 + l4 * 8];
        #pragma unroll
        for (int nf = 0; nf < 4; nf++)
            bfr[nf] = *(const short8*)(wbase + (size_t)nf * 16 * KPAD + ks * 32);
        #pragma unroll
        for (int mf = 0; mf < 4; mf++)
            #pragma unroll
            for (int nf = 0; nf < 4; nf++)
                acc[mf][nf] = __builtin_amdgcn_mfma_f32_16x16x32_bf16(af[mf], bfr[nf], acc[mf][nf], 0, 0, 0);
    }
    __syncthreads();   // A tile dead; reuse LDS for output staging

    if (nb == 1 || nb == 2) {
        #pragma unroll
        for (int nf = 0; nf < 4; nf++) {
            int col = wn * 64 + nf * 16 + l15;
            float bv = bias[nb * 128 + col];
            #pragma unroll
            for (int mf = 0; mf < 4; mf++)
                #pragma unroll
                for (int rr = 0; rr < 4; rr++)
                    Alds[wm * 64 + mf * 16 + l4 * 4 + rr][col] = f2bf(acc[mf][nf][rr] + bv);
        }
        __syncthreads();
        int off = (nb == 1) ? 0 : 128;
        #pragma unroll
        for (int it = 0; it < 8; it++) {
            int idx = it * 256 + tid;
            int row = idx >> 4, c8 = (idx & 15) * 8;
            if (rowbase + row < n) {
                uint4 v = *(const uint4*)&Alds[row][c8];
                *(uint4*)(KVp + (size_t)(rowbase + row) * 256 + off + c8) = v;
            }
        }
    } else {
        float* Yp = (nb == 0) ? Qp : Hp;
        float scale = (nb == 0) ? ATT_SCALE : 1.f;
        float (*Sf)[68] = (float (*)[68])Alds;
        #pragma unroll
        for (int h = 0; h < 2; h++) {
            if (wn == h) {
                #pragma unroll
                for (int nf = 0; nf < 4; nf++) {
                    int col = wn * 64 + nf * 16 + l15;
                    float bv = bias[nb * 128 + col];
                    #pragma unroll
                    for (int mf = 0; mf < 4; mf++)
                        #pragma unroll
                        for (int rr = 0; rr < 4; rr++)
                            Sf[wm * 64 + mf * 16 + l4 * 4 + rr][nf * 16 + l15] =
                                (acc[mf][nf][rr] + bv) * scale;
                }
            }
            __syncthreads();
            #pragma unroll
            for (int it = 0; it < 8; it++) {
                int idx = it * 256 + tid;
                int row = idx >> 4, c4 = (idx & 15) * 4;
                if (rowbase + row < n) {
                    float4 v = *(const float4*)&Sf[row][c4];
                    *(float4*)(Yp + (size_t)(rowbase + row) * OUTF + h * 64 + c4) = v;
                }
            }
            if (h == 0) __syncthreads();
        }
    }
}

// ---------- fused dual-layer edge GEMM: 5 tiles/block, reg prefetch (R15-proven), bf16 EE1/EE2 ----------
__global__ __launch_bounds__(256) void edge_mfma_fused(
    const float* __restrict__ EA,
    const unsigned short* __restrict__ WmT1, const unsigned short* __restrict__ WmT2,
    unsigned short* __restrict__ EE1, unsigned short* __restrict__ EE2)
{
    __shared__ unsigned short Tlds[64][ASTR];   // transpose buffer (wave-private quadrants)
    int tid = threadIdx.x;
    int lane = tid & 63, w = tid >> 6;
    int l15 = lane & 15, l4 = lane >> 4;
    int rbase = w * 16;
    int tile0 = blockIdx.x * ETILES;

    auto load_tile = [&](int tile, short8* af) {
        const float* rp = EA + (size_t)(tile * 64 + rbase + l15) * KE;
        float etf = rp[3];
        #pragma unroll
        for (int ks = 0; ks < 4; ks++) {
            int cbase = ks * 32 + l4 * 8;
            float2 t0 = make_float2(0.f, 0.f), t1 = t0, t2 = t0, t3 = t0;
            if (cbase + 2 <= KE) t0 = *(const float2*)(rp + cbase);
            if (cbase + 4 <= KE) t1 = *(const float2*)(rp + cbase + 2);
            if (cbase + 6 <= KE) t2 = *(const float2*)(rp + cbase + 4);
            if (cbase + 8 <= KE) t3 = *(const float2*)(rp + cbase + 6);
            float fv[8] = {t0.x, t0.y, t1.x, t1.y, t2.x, t2.y, t3.x, t3.y};
            #pragma unroll
            for (int j = 0; j < 8; j++) {
                int col = cbase + j;
                float v = (col == 3) ? 0.f : fv[j];    // col 3 = etype -> zero
                af[ks][j] = f2bf(v);
            }
        }
        int oh = KE + (int)etf;                        // one-hot col 118..121 (ks==3 chunk)
        #pragma unroll
        for (int j = 0; j < 8; j++) {
            int col = 96 + l4 * 8 + j;
            if (col == oh) af[3][j] = 0x3F80;          // bf16 1.0
        }
    };
    auto do_layer = [&](const unsigned short* __restrict__ WmT, unsigned short* __restrict__ EEc,
                        int e0, const short8* af) {
        f32x4 acc[8];
        #pragma unroll
        for (int nf = 0; nf < 8; nf++) acc[nf] = (f32x4){0.f, 0.f, 0.f, 0.f};

        #pragma unroll
        for (int ks = 0; ks < 4; ks++) {
            short8 bfr[8];
            #pragma unroll
            for (int nf = 0; nf < 8; nf++)
                bfr[nf] = *(const short8*)(WmT + (size_t)(nf * 16 + l15) * KPAD + ks * 32 + l4 * 8);
            #pragma unroll
            for (int nf = 0; nf < 8; nf++)
                acc[nf] = __builtin_amdgcn_mfma_f32_16x16x32_bf16(af[ks], bfr[nf], acc[nf], 0, 0, 0);
        }
        // wave-private transpose through own LDS rows (no barrier), coalesced linear store
        #pragma unroll
        for (int nf = 0; nf < 8; nf++)
            #pragma unroll
            for (int rr = 0; rr < 4; rr++)
                Tlds[rbase + l4 * 4 + rr][nf * 16 + l15] = f2bf(acc[nf][rr]);
        #pragma unroll
        for (int it = 0; it < 4; it++) {
            int t2 = it * 64 + lane;
            int rid = t2 >> 4, c8 = (t2 & 15) * 8;     // rid spans [0,16) over it=0..3
            uint4 v = *(const uint4*)&Tlds[rbase + rid][c8];
            *(uint4*)(EEc + ((size_t)(e0 + rbase + rid)) * 128 + c8) = v;
        }
    };

    short8 afA[4];
    load_tile(tile0, afA);

    #pragma unroll
    for (int t = 0; t < ETILES; t++) {
        int e0 = (tile0 + t) * 64;
        do_layer(WmT1, EE1, e0, afA);
        short8 afB[4];
        if (t + 1 < ETILES) load_tile(tile0 + t + 1, afB);   // loads in flight under layer 2
        do_layer(WmT2, EE2, e0, afA);
        if (t + 1 < ETILES) {
            afA[0] = afB[0]; afA[1] = afB[1]; afA[2] = afB[2]; afA[3] = afB[3];
        }
    }
}

// ---------- fused attn: one wave per dst, online softmax, 3-deep pipeline, int2 indices ----------
__global__ __launch_bounds__(256) void attn_node(
    const float* __restrict__ Qp, const unsigned short* __restrict__ KVp,
    const unsigned short* __restrict__ EEc,
    const int* __restrict__ row_start, const int2* __restrict__ csr_pair,
    const float* __restrict__ Hskip, float* __restrict__ Out)
{
    int lane = threadIdx.x & 63;
    int gw = (int)((blockIdx.x * (size_t)blockDim.x + threadIdx.x) >> 6);
    int nW = (gridDim.x * blockDim.x) >> 6;
    int c2 = lane * 2;

    for (int d = gw; d < NN; d += nW) {
        int rs = row_start[d], re = row_start[d + 1];
        float2 q = *(const float2*)(Qp + (size_t)d * OUTF + c2);
        float m = -3.4e38f, s = 0.f, a0 = 0.f, a1 = 0.f;

        int j0 = (rs < re) ? rs : 0;
        int jlast = (rs < re) ? re - 1 : 0;
        int j1 = (j0 + 1 <= jlast) ? j0 + 1 : jlast;
        int j2 = (j0 + 2 <= jlast) ? j0 + 2 : jlast;
        int2 prA = csr_pair[j0];
        int2 prB = csr_pair[j1];
        int2 prC = csr_pair[j2];
        unsigned kA = *(const unsigned*)(KVp + (size_t)prA.x * 256 + c2);
        unsigned vA = *(const unsigned*)(KVp + (size_t)prA.x * 256 + 128 + c2);
        unsigned eA = *(const unsigned*)(EEc + (size_t)prA.y * 128 + c2);
        unsigned kB = *(const unsigned*)(KVp + (size_t)prB.x * 256 + c2);
        unsigned vB = *(const unsigned*)(KVp + (size_t)prB.x * 256 + 128 + c2);
        unsigned eB = *(const unsigned*)(EEc + (size_t)prB.y * 128 + c2);

        for (int j = rs; j < re; j++) {
            unsigned kC = *(const unsigned*)(KVp + (size_t)prC.x * 256 + c2);
            unsigned vC = *(const unsigned*)(KVp + (size_t)prC.x * 256 + 128 + c2);
            unsigned eC = *(const unsigned*)(EEc + (size_t)prC.y * 128 + c2);
            int j3 = (j + 3 <= jlast) ? j + 3 : jlast;
            int2 prD = csr_pair[j3];

            float e0 = bf2f((unsigned short)(eA & 0xFFFFu));
            float e1 = bf2f((unsigned short)(eA >> 16));
            float k0 = bf2f((unsigned short)(kA & 0xFFFFu));
            float k1 = bf2f((unsigned short)(kA >> 16));
            float v0 = bf2f((unsigned short)(vA & 0xFFFFu));
            float v1 = bf2f((unsigned short)(vA >> 16));

            float t = q.x * (k0 + e0) + q.y * (k1 + e1);
            t += __shfl_xor(t, 1); t += __shfl_xor(t, 2);
            t += __shfl_xor(t, 4); t += __shfl_xor(t, 8);
            float alpha = t;   // ATT_SCALE pre-folded into Q
            float mn = fmaxf(m, alpha);
            float r = __expf(m - mn);
            float p = __expf(alpha - mn);
            s = s * r + p;
            a0 = a0 * r + p * (v0 + e0);
            a1 = a1 * r + p * (v1 + e1);
            m = mn;
            kA = kB; vA = vB; eA = eB;
            kB = kC; vB = vC; eB = eC;
            prC = prD;
        }
        float inv = 1.f / (s + 1e-16f);
        float2 h = *(const float2*)(Hskip + (size_t)d * OUTF + c2);
        float2 o;
        o.x = a0 * inv + h.x;
        o.y = a1 * inv + h.y;
        *(float2*)(Out + (size_t)d * OUTF + c2) = o;
    }
}

extern "C" void kernel_launch(void* const* d_in, const int* in_sizes, int n_in,
                              void* d_out, int out_size, void* d_ws, size_t ws_size,
                              hipStream_t stream) {
    const float* x    = (const float*)d_in[0];
    const int*   ei   = (const int*)d_in[1];
    const float* ea   = (const float*)d_in[2];
    const float* emb  = (const float*)d_in[3];
    const float* w1q  = (const float*)d_in[4];  const float* b1q = (const float*)d_in[5];
    const float* w1k  = (const float*)d_in[6];  const float* b1k = (const float*)d_in[7];
    const float* w1v  = (const float*)d_in[8];  const float* b1v = (const float*)d_in[9];
    const float* w1e  = (const float*)d_in[10];
    const float* w1s  = (const float*)d_in[11]; const float* b1s = (const float*)d_in[12];
    const float* w2q  = (const float*)d_in[13]; const float* b2q = (const float*)d_in[14];
    const float* w2k  = (const float*)d_in[15]; const float* b2k = (const float*)d_in[16];
    const float* w2v  = (const float*)d_in[17]; const float* b2v = (const float*)d_in[18];
    const float* w2e  = (const float*)d_in[19];
    const float* w2s  = (const float*)d_in[20]; const float* b2s = (const float*)d_in[21];

    const int* srcI = ei;
    const int* dstI = ei + NE;

    float* Q = (float*)d_ws;                                        // N x 128 f32 (pre-scaled)
    unsigned short* KV = (unsigned short*)(Q + (size_t)NN * OUTF);  // N x 256 bf16 [K|V]
    float* H = (float*)(KV + (size_t)NN * 256);                     // N x 128 f32
    unsigned short* EE1 = (unsigned short*)(H + (size_t)NN * OUTF); // E x 128 bf16
    unsigned short* EE2 = EE1 + (size_t)NE * 128;                   // E x 128 bf16
    int2* csr_pair = (int2*)(EE2 + (size_t)NE * 128);               // E x {src, eid}
    int* row_start = (int*)(csr_pair + NE);   // N+1
    int* cursor    = row_start + NN + 1;
    int* cnt       = cursor + NN;
    int* S1        = cnt + NN;
    int* bsum      = S1 + NN;
    int* boff      = bsum + NSCANB;
    unsigned short* WT1  = (unsigned short*)(boff + NSCANB + 1);
    unsigned short* WT2  = WT1 + 512 * KPAD;
    unsigned short* WmT1 = WT2 + 512 * KPAD;
    unsigned short* WmT2 = WmT1 + OUTF * KPAD;
    float* bias1 = (float*)(WmT2 + OUTF * KPAD);
    float* bias2 = bias1 + 512;

    prep_weights<<<128, 256, 0, stream>>>(w1q, w1k, w1v, w1s, w2q, w2k, w2v, w2s,
                                          w1e, w2e, emb,
                                          b1q, b1k, b1v, b1s, b2q, b2k, b2v, b2s,
                                          WT1, WT2, WmT1, WmT2, bias1, bias2);
    hipMemsetAsync(cnt, 0, (size_t)NN * sizeof(int), stream);
    hist_kernel<<<NE / 256, 256, 0, stream>>>(dstI, cnt);
    scan1<<<NSCANB, 256, 0, stream>>>(cnt, S1, bsum);
    scan2<<<1, 512, 0, stream>>>(bsum, boff);
    scan3<<<NSCANB, 256, 0, stream>>>(S1, boff, cnt, row_start, cursor);
    scatter_csr<<<NE / 256, 256, 0, stream>>>(srcI, dstI, cursor, csr_pair);

    int ngrid = ((NN + 127) / 128) * 4;   // 782 row-tiles x 4 col-blocks = 3128
    int egrid = NE / (64 * ETILES);       // 2000

    // ---- node features L1 + fused dual-layer edge GEMM (pipelined, barrier-free) ----
    node_mfma<<<ngrid, 256, 0, stream>>>(x, K1, K1, 0, NN, WT1, bias1, Q, KV, H);
    edge_mfma_fused<<<egrid, 256, 0, stream>>>(ea, WmT1, WmT2, EE1, EE2);
    attn_node<<<4096, 256, 0, stream>>>(Q, KV, EE1, row_start, csr_pair, H, H);

    // ---- layer 2 ----
    node_mfma<<<ngrid, 256, 0, stream>>>(H, OUTF, OUTF, 1, NN, WT2, bias2, Q, KV, (float*)d_out);
    attn_node<<<4096, 256, 0, stream>>>(Q, KV, EE2, row_start, csr_pair, (float*)d_out, (float*)d_out);
}

// Round 21
// 966.558 us; speedup vs baseline: 1.0816x; 1.0112x over previous
//
#include <hip/hip_runtime.h>

#define NN 100000
#define NE 640000
#define OUTF 128
#define K1 100
#define KE 118
#define KPAD 128
#define ASTR 136              // padded LDS row stride (ushorts)
#define ATT_SCALE 0.17677669529663687f
#define NSCANB 391            // ceil(NN/256)
#define ETILES 5              // tiles per edge block (NE/64/2000)
#define EGRID 2000            // NE/(64*ETILES)
#define NGRID4 3128           // 782 row-tiles * 4 col-blocks
#define SGRID 2500            // NE/256

typedef __attribute__((ext_vector_type(8))) short short8;
typedef __attribute__((ext_vector_type(4))) float f32x4;

__device__ __forceinline__ unsigned short f2bf(float f) {
    unsigned u = __float_as_uint(f);
    u += 0x7FFFu + ((u >> 16) & 1u);   // RNE
    return (unsigned short)(u >> 16);
}
__device__ __forceinline__ float bf2f(unsigned short h) {
    return __uint_as_float(((unsigned)h) << 16);
}

// ---------- prep: transposed bf16 weights [col][k]; WmT rows 118-121 = one-hot etype tables ----------
__global__ void prep_weights(
    const float* __restrict__ w1q, const float* __restrict__ w1k,
    const float* __restrict__ w1v, const float* __restrict__ w1s,
    const float* __restrict__ w2q, const float* __restrict__ w2k,
    const float* __restrict__ w2v, const float* __restrict__ w2s,
    const float* __restrict__ we1, const float* __restrict__ we2,
    const float* __restrict__ emb,
    const float* __restrict__ b1q, const float* __restrict__ b1k,
    const float* __restrict__ b1v, const float* __restrict__ b1s,
    const float* __restrict__ b2q, const float* __restrict__ b2k,
    const float* __restrict__ b2v, const float* __restrict__ b2s,
    unsigned short* __restrict__ WT1, unsigned short* __restrict__ WT2,
    unsigned short* __restrict__ WmT1, unsigned short* __restrict__ WmT2,
    float* __restrict__ bias1, float* __restrict__ bias2)
{
    int idx = blockIdx.x * blockDim.x + threadIdx.x;
    int stride = gridDim.x * blockDim.x;
    for (int i = idx; i < 512 * KPAD; i += stride) {
        int col = i >> 7, k = i & 127;
        int which = col >> 7, c = col & 127;
        const float* s1 = (which == 0) ? w1q : (which == 1) ? w1k : (which == 2) ? w1v : w1s;
        const float* s2 = (which == 0) ? w2q : (which == 1) ? w2k : (which == 2) ? w2v : w2s;
        float v1 = (k < K1) ? s1[k * OUTF + c] : 0.f;
        float v2 = s2[k * OUTF + c];
        WT1[i] = f2bf(v1); WT2[i] = f2bf(v2);
    }
    for (int i = idx; i < OUTF * KPAD; i += stride) {
        int col = i >> 7, k = i & 127;
        float v1 = 0.f, v2 = 0.f;
        if (k < 3)                 { v1 = we1[k * OUTF + col];       v2 = we2[k * OUTF + col]; }
        else if (k >= 4 && k < KE) { v1 = we1[(k - 1) * OUTF + col]; v2 = we2[(k - 1) * OUTF + col]; }
        else if (k >= KE && k < KE + 4) {
            int t = k - KE;
            #pragma unroll
            for (int r = 0; r < 8; r++) {
                float ev = emb[t * 8 + r];
                v1 += ev * we1[(117 + r) * OUTF + col];
                v2 += ev * we2[(117 + r) * OUTF + col];
            }
        }
        WmT1[i] = f2bf(v1); WmT2[i] = f2bf(v2);
    }
    for (int i = idx; i < 512; i += stride) {
        int which = i >> 7, c = i & 127;
        const float* sb1 = (which == 0) ? b1q : (which == 1) ? b1k : (which == 2) ? b1v : b1s;
        const float* sb2 = (which == 0) ? b2q : (which == 1) ? b2k : (which == 2) ? b2v : b2s;
        bias1[i] = sb1[c]; bias2[i] = sb2[c];
    }
}

// ---------- CSR build (hist + scans; scatter lives in the mega kernel) ----------
__global__ void hist_kernel(const int* __restrict__ dstI, int* __restrict__ cnt) {
    int e = blockIdx.x * 256 + threadIdx.x;
    if (e < NE) atomicAdd(&cnt[dstI[e]], 1);
}
__global__ void scan1(const int* __restrict__ cnt, int* __restrict__ S1, int* __restrict__ bsum) {
    __shared__ int sd[256];
    int t = blockIdx.x * 256 + threadIdx.x;
    sd[threadIdx.x] = (t < NN) ? cnt[t] : 0;
    __syncthreads();
    for (int off = 1; off < 256; off <<= 1) {
        int x = (threadIdx.x >= off) ? sd[threadIdx.x - off] : 0;
        __syncthreads();
        sd[threadIdx.x] += x;
        __syncthreads();
    }
    if (t < NN) S1[t] = sd[threadIdx.x];
    if (threadIdx.x == 255) bsum[blockIdx.x] = sd[255];
}
__global__ void scan2(const int* __restrict__ bsum, int* __restrict__ boff) {
    __shared__ int sd[512];
    int t = threadIdx.x;
    sd[t] = (t < NSCANB) ? bsum[t] : 0;
    __syncthreads();
    for (int off = 1; off < 512; off <<= 1) {
        int x = (t >= off) ? sd[t - off] : 0;
        __syncthreads();
        sd[t] += x;
        __syncthreads();
    }
    if (t < NSCANB) boff[t] = (t == 0) ? 0 : sd[t - 1];
}
__global__ void scan3(const int* __restrict__ S1, const int* __restrict__ boff,
                      const int* __restrict__ cnt,
                      int* __restrict__ row_start, int* __restrict__ cursor) {
    int t = blockIdx.x * 256 + threadIdx.x;
    if (t < NN) {
        int incl = S1[t] + boff[t >> 8];
        row_start[t + 1] = incl;
        cursor[t] = incl - cnt[t];
        if (t == 0) row_start[0] = 0;
    }
}

// ---------- node GEMM body (one 128-col block per block; coalesced LDS-staged epilogue) ----------
__device__ __forceinline__ void node_body(
    int nbid, unsigned short (*Alds)[ASTR],
    const float* __restrict__ X, int ldx, int Kdim, int relu, int n,
    const unsigned short* __restrict__ WT, const float* __restrict__ bias,
    float* __restrict__ Qp, unsigned short* __restrict__ KVp, float* __restrict__ Hp)
{
    int tid = threadIdx.x;
    int rowbase = (nbid >> 2) * 128;
    int nb = nbid & 3;

    for (int idx = tid; idx < 128 * 68; idx += 256) {
        int r = idx / 68, kv = idx % 68;
        int k = kv * 2;
        float2 v = make_float2(0.f, 0.f);
        int gr = rowbase + r;
        if (gr < n && k < Kdim) v = *(const float2*)(X + (size_t)gr * ldx + k);
        if (relu) { v.x = fmaxf(v.x, 0.f); v.y = fmaxf(v.y, 0.f); }
        unsigned pv = (unsigned)f2bf(v.x) | ((unsigned)f2bf(v.y) << 16);
        *(unsigned*)&Alds[r][k] = pv;
    }
    __syncthreads();

    int lane = tid & 63, wid = tid >> 6;
    int wm = wid >> 1, wn = wid & 1;
    int l15 = lane & 15, l4 = lane >> 4;

    f32x4 acc[4][4];
    #pragma unroll
    for (int mf = 0; mf < 4; mf++)
        #pragma unroll
        for (int nf = 0; nf < 4; nf++)
            acc[mf][nf] = (f32x4){0.f, 0.f, 0.f, 0.f};

    const unsigned short* wbase = WT + (size_t)(nb * 128 + wn * 64 + l15) * KPAD + l4 * 8;
    #pragma unroll
    for (int ks = 0; ks < 4; ks++) {
        short8 af[4], bfr[4];
        #pragma unroll
        for (int mf = 0; mf < 4; mf++)
            af[mf] = *(const short8*)&Alds[wm * 64 + mf * 16 + l15][ks * 32 + l4 * 8];
        #pragma unroll
        for (int nf = 0; nf < 4; nf++)
            bfr[nf] = *(const short8*)(wbase + (size_t)nf * 16 * KPAD + ks * 32);
        #pragma unroll
        for (int mf = 0; mf < 4; mf++)
            #pragma unroll
            for (int nf = 0; nf < 4; nf++)
                acc[mf][nf] = __builtin_amdgcn_mfma_f32_16x16x32_bf16(af[mf], bfr[nf], acc[mf][nf], 0, 0, 0);
    }
    __syncthreads();   // A tile dead; reuse LDS for output staging

    if (nb == 1 || nb == 2) {
        #pragma unroll
        for (int nf = 0; nf < 4; nf++) {
            int col = wn * 64 + nf * 16 + l15;
            float bv = bias[nb * 128 + col];
            #pragma unroll
            for (int mf = 0; mf < 4; mf++)
                #pragma unroll
                for (int rr = 0; rr < 4; rr++)
                    Alds[wm * 64 + mf * 16 + l4 * 4 + rr][col] = f2bf(acc[mf][nf][rr] + bv);
        }
        __syncthreads();
        int off = (nb == 1) ? 0 : 128;
        #pragma unroll
        for (int it = 0; it < 8; it++) {
            int idx = it * 256 + tid;
            int row = idx >> 4, c8 = (idx & 15) * 8;
            if (rowbase + row < n) {
                uint4 v = *(const uint4*)&Alds[row][c8];
                *(uint4*)(KVp + (size_t)(rowbase + row) * 256 + off + c8) = v;
            }
        }
    } else {
        float* Yp = (nb == 0) ? Qp : Hp;
        float scale = (nb == 0) ? ATT_SCALE : 1.f;
        float (*Sf)[68] = (float (*)[68])Alds;
        #pragma unroll
        for (int h = 0; h < 2; h++) {
            if (wn == h) {
                #pragma unroll
                for (int nf = 0; nf < 4; nf++) {
                    int col = wn * 64 + nf * 16 + l15;
                    float bv = bias[nb * 128 + col];
                    #pragma unroll
                    for (int mf = 0; mf < 4; mf++)
                        #pragma unroll
                        for (int rr = 0; rr < 4; rr++)
                            Sf[wm * 64 + mf * 16 + l4 * 4 + rr][nf * 16 + l15] =
                                (acc[mf][nf][rr] + bv) * scale;
                }
            }
            __syncthreads();
            #pragma unroll
            for (int it = 0; it < 8; it++) {
                int idx = it * 256 + tid;
                int row = idx >> 4, c4 = (idx & 15) * 4;
                if (rowbase + row < n) {
                    float4 v = *(const float4*)&Sf[row][c4];
                    *(float4*)(Yp + (size_t)(rowbase + row) * OUTF + h * 64 + c4) = v;
                }
            }
            if (h == 0) __syncthreads();
        }
    }
}

// ---------- fused dual-layer edge GEMM body (R15/R20-proven: reg prefetch, zero barriers) ----------
__device__ __forceinline__ void edge_body(
    int ebid, unsigned short (*Tlds)[ASTR],
    const float* __restrict__ EA,
    const unsigned short* __restrict__ WmT1, const unsigned short* __restrict__ WmT2,
    unsigned short* __restrict__ EE1, unsigned short* __restrict__ EE2)
{
    int tid = threadIdx.x;
    int lane = tid & 63, w = tid >> 6;
    int l15 = lane & 15, l4 = lane >> 4;
    int rbase = w * 16;
    int tile0 = ebid * ETILES;

    auto load_tile = [&](int tile, short8* af) {
        const float* rp = EA + (size_t)(tile * 64 + rbase + l15) * KE;
        float etf = rp[3];
        #pragma unroll
        for (int ks = 0; ks < 4; ks++) {
            int cbase = ks * 32 + l4 * 8;
            float2 t0 = make_float2(0.f, 0.f), t1 = t0, t2 = t0, t3 = t0;
            if (cbase + 2 <= KE) t0 = *(const float2*)(rp + cbase);
            if (cbase + 4 <= KE) t1 = *(const float2*)(rp + cbase + 2);
            if (cbase + 6 <= KE) t2 = *(const float2*)(rp + cbase + 4);
            if (cbase + 8 <= KE) t3 = *(const float2*)(rp + cbase + 6);
            float fv[8] = {t0.x, t0.y, t1.x, t1.y, t2.x, t2.y, t3.x, t3.y};
            #pragma unroll
            for (int j = 0; j < 8; j++) {
                int col = cbase + j;
                float v = (col == 3) ? 0.f : fv[j];    // col 3 = etype -> zero
                af[ks][j] = f2bf(v);
            }
        }
        int oh = KE + (int)etf;                        // one-hot col 118..121 (ks==3 chunk)
        #pragma unroll
        for (int j = 0; j < 8; j++) {
            int col = 96 + l4 * 8 + j;
            if (col == oh) af[3][j] = 0x3F80;          // bf16 1.0
        }
    };
    auto do_layer = [&](const unsigned short* __restrict__ WmT, unsigned short* __restrict__ EEc,
                        int e0, const short8* af) {
        f32x4 acc[8];
        #pragma unroll
        for (int nf = 0; nf < 8; nf++) acc[nf] = (f32x4){0.f, 0.f, 0.f, 0.f};

        #pragma unroll
        for (int ks = 0; ks < 4; ks++) {
            short8 bfr[8];
            #pragma unroll
            for (int nf = 0; nf < 8; nf++)
                bfr[nf] = *(const short8*)(WmT + (size_t)(nf * 16 + l15) * KPAD + ks * 32 + l4 * 8);
            #pragma unroll
            for (int nf = 0; nf < 8; nf++)
                acc[nf] = __builtin_amdgcn_mfma_f32_16x16x32_bf16(af[ks], bfr[nf], acc[nf], 0, 0, 0);
        }
        // wave-private transpose through own LDS rows (no barrier), coalesced linear store
        #pragma unroll
        for (int nf = 0; nf < 8; nf++)
            #pragma unroll
            for (int rr = 0; rr < 4; rr++)
                Tlds[rbase + l4 * 4 + rr][nf * 16 + l15] = f2bf(acc[nf][rr]);
        #pragma unroll
        for (int it = 0; it < 4; it++) {
            int t2 = it * 64 + lane;
            int rid = t2 >> 4, c8 = (t2 & 15) * 8;     // rid spans [0,16) over it=0..3
            uint4 v = *(const uint4*)&Tlds[rbase + rid][c8];
            *(uint4*)(EEc + ((size_t)(e0 + rbase + rid)) * 128 + c8) = v;
        }
    };

    short8 afA[4];
    load_tile(tile0, afA);

    #pragma unroll
    for (int t = 0; t < ETILES; t++) {
        int e0 = (tile0 + t) * 64;
        do_layer(WmT1, EE1, e0, afA);
        short8 afB[4];
        if (t + 1 < ETILES) load_tile(tile0 + t + 1, afB);   // loads in flight under layer 2
        do_layer(WmT2, EE2, e0, afA);
        if (t + 1 < ETILES) {
            afA[0] = afB[0]; afA[1] = afB[1]; afA[2] = afB[2]; afA[3] = afB[3];
        }
    }
}

// ---------- MEGA layer-1 dispatch: edge blocks [0,EGRID) | node blocks | scatter blocks ----------
// All three sub-kernels are mutually independent; co-residency lets node/scatter waves fill the
// CU cycles the latency-bound edge waves leave idle.
__global__ __launch_bounds__(256) void mega_l1(
    // edge
    const float* __restrict__ EA,
    const unsigned short* __restrict__ WmT1, const unsigned short* __restrict__ WmT2,
    unsigned short* __restrict__ EE1, unsigned short* __restrict__ EE2,
    // node (layer 1)
    const float* __restrict__ X,
    const unsigned short* __restrict__ WT, const float* __restrict__ bias,
    float* __restrict__ Qp, unsigned short* __restrict__ KVp, float* __restrict__ Hp,
    // scatter
    const int* __restrict__ srcI, const int* __restrict__ dstI,
    int* __restrict__ cursor, int2* __restrict__ csr_pair)
{
    __shared__ unsigned short Alds[128][ASTR];
    int bid = blockIdx.x;
    if (bid < EGRID) {
        edge_body(bid, Alds, EA, WmT1, WmT2, EE1, EE2);
    } else if (bid < EGRID + NGRID4) {
        node_body(bid - EGRID, Alds, X, K1, K1, 0, NN, WT, bias, Qp, KVp, Hp);
    } else {
        int e = (bid - EGRID - NGRID4) * 256 + threadIdx.x;
        if (e < NE) {
            int j = atomicAdd(&cursor[dstI[e]], 1);
            csr_pair[j] = make_int2(srcI[e], e);
        }
    }
}

// ---------- standalone node GEMM (layer 2) ----------
__global__ __launch_bounds__(256) void node_mfma(
    const float* __restrict__ X, int ldx, int Kdim, int relu, int n,
    const unsigned short* __restrict__ WT, const float* __restrict__ bias,
    float* __restrict__ Qp, unsigned short* __restrict__ KVp, float* __restrict__ Hp)
{
    __shared__ unsigned short Alds[128][ASTR];
    node_body(blockIdx.x, Alds, X, ldx, Kdim, relu, n, WT, bias, Qp, KVp, Hp);
}

// ---------- fused attn: one wave per dst, online softmax, 3-deep pipeline, int2 indices ----------
__global__ __launch_bounds__(256) void attn_node(
    const float* __restrict__ Qp, const unsigned short* __restrict__ KVp,
    const unsigned short* __restrict__ EEc,
    const int* __restrict__ row_start, const int2* __restrict__ csr_pair,
    const float* __restrict__ Hskip, float* __restrict__ Out)
{
    int lane = threadIdx.x & 63;
    int gw = (int)((blockIdx.x * (size_t)blockDim.x + threadIdx.x) >> 6);
    int nW = (gridDim.x * blockDim.x) >> 6;
    int c2 = lane * 2;

    for (int d = gw; d < NN; d += nW) {
        int rs = row_start[d], re = row_start[d + 1];
        float2 q = *(const float2*)(Qp + (size_t)d * OUTF + c2);
        float m = -3.4e38f, s = 0.f, a0 = 0.f, a1 = 0.f;

        int j0 = (rs < re) ? rs : 0;
        int jlast = (rs < re) ? re - 1 : 0;
        int j1 = (j0 + 1 <= jlast) ? j0 + 1 : jlast;
        int j2 = (j0 + 2 <= jlast) ? j0 + 2 : jlast;
        int2 prA = csr_pair[j0];
        int2 prB = csr_pair[j1];
        int2 prC = csr_pair[j2];
        unsigned kA = *(const unsigned*)(KVp + (size_t)prA.x * 256 + c2);
        unsigned vA = *(const unsigned*)(KVp + (size_t)prA.x * 256 + 128 + c2);
        unsigned eA = *(const unsigned*)(EEc + (size_t)prA.y * 128 + c2);
        unsigned kB = *(const unsigned*)(KVp + (size_t)prB.x * 256 + c2);
        unsigned vB = *(const unsigned*)(KVp + (size_t)prB.x * 256 + 128 + c2);
        unsigned eB = *(const unsigned*)(EEc + (size_t)prB.y * 128 + c2);

        for (int j = rs; j < re; j++) {
            unsigned kC = *(const unsigned*)(KVp + (size_t)prC.x * 256 + c2);
            unsigned vC = *(const unsigned*)(KVp + (size_t)prC.x * 256 + 128 + c2);
            unsigned eC = *(const unsigned*)(EEc + (size_t)prC.y * 128 + c2);
            int j3 = (j + 3 <= jlast) ? j + 3 : jlast;
            int2 prD = csr_pair[j3];

            float e0 = bf2f((unsigned short)(eA & 0xFFFFu));
            float e1 = bf2f((unsigned short)(eA >> 16));
            float k0 = bf2f((unsigned short)(kA & 0xFFFFu));
            float k1 = bf2f((unsigned short)(kA >> 16));
            float v0 = bf2f((unsigned short)(vA & 0xFFFFu));
            float v1 = bf2f((unsigned short)(vA >> 16));

            float t = q.x * (k0 + e0) + q.y * (k1 + e1);
            t += __shfl_xor(t, 1); t += __shfl_xor(t, 2);
            t += __shfl_xor(t, 4); t += __shfl_xor(t, 8);
            float alpha = t;   // ATT_SCALE pre-folded into Q
            float mn = fmaxf(m, alpha);
            float r = __expf(m - mn);
            float p = __expf(alpha - mn);
            s = s * r + p;
            a0 = a0 * r + p * (v0 + e0);
            a1 = a1 * r + p * (v1 + e1);
            m = mn;
            kA = kB; vA = vB; eA = eB;
            kB = kC; vB = vC; eB = eC;
            prC = prD;
        }
        float inv = 1.f / (s + 1e-16f);
        float2 h = *(const float2*)(Hskip + (size_t)d * OUTF + c2);
        float2 o;
        o.x = a0 * inv + h.x;
        o.y = a1 * inv + h.y;
        *(float2*)(Out + (size_t)d * OUTF + c2) = o;
    }
}

extern "C" void kernel_launch(void* const* d_in, const int* in_sizes, int n_in,
                              void* d_out, int out_size, void* d_ws, size_t ws_size,
                              hipStream_t stream) {
    const float* x    = (const float*)d_in[0];
    const int*   ei   = (const int*)d_in[1];
    const float* ea   = (const float*)d_in[2];
    const float* emb  = (const float*)d_in[3];
    const float* w1q  = (const float*)d_in[4];  const float* b1q = (const float*)d_in[5];
    const float* w1k  = (const float*)d_in[6];  const float* b1k = (const float*)d_in[7];
    const float* w1v  = (const float*)d_in[8];  const float* b1v = (const float*)d_in[9];
    const float* w1e  = (const float*)d_in[10];
    const float* w1s  = (const float*)d_in[11]; const float* b1s = (const float*)d_in[12];
    const float* w2q  = (const float*)d_in[13]; const float* b2q = (const float*)d_in[14];
    const float* w2k  = (const float*)d_in[15]; const float* b2k = (const float*)d_in[16];
    const float* w2v  = (const float*)d_in[17]; const float* b2v = (const float*)d_in[18];
    const float* w2e  = (const float*)d_in[19];
    const float* w2s  = (const float*)d_in[20]; const float* b2s = (const float*)d_in[21];

    const int* srcI = ei;
    const int* dstI = ei + NE;

    float* Q = (float*)d_ws;                                        // N x 128 f32 (pre-scaled)
    unsigned short* KV = (unsigned short*)(Q + (size_t)NN * OUTF);  // N x 256 bf16 [K|V]
    float* H = (float*)(KV + (size_t)NN * 256);                     // N x 128 f32
    unsigned short* EE1 = (unsigned short*)(H + (size_t)NN * OUTF); // E x 128 bf16
    unsigned short* EE2 = EE1 + (size_t)NE * 128;                   // E x 128 bf16
    int2* csr_pair = (int2*)(EE2 + (size_t)NE * 128);               // E x {src, eid}
    int* row_start = (int*)(csr_pair + NE);   // N+1
    int* cursor    = row_start + NN + 1;
    int* cnt       = cursor + NN;
    int* S1        = cnt + NN;
    int* bsum      = S1 + NN;
    int* boff      = bsum + NSCANB;
    unsigned short* WT1  = (unsigned short*)(boff + NSCANB + 1);
    unsigned short* WT2  = WT1 + 512 * KPAD;
    unsigned short* WmT1 = WT2 + 512 * KPAD;
    unsigned short* WmT2 = WmT1 + OUTF * KPAD;
    float* bias1 = (float*)(WmT2 + OUTF * KPAD);
    float* bias2 = bias1 + 512;

    prep_weights<<<128, 256, 0, stream>>>(w1q, w1k, w1v, w1s, w2q, w2k, w2v, w2s,
                                          w1e, w2e, emb,
                                          b1q, b1k, b1v, b1s, b2q, b2k, b2v, b2s,
                                          WT1, WT2, WmT1, WmT2, bias1, bias2);
    hipMemsetAsync(cnt, 0, (size_t)NN * sizeof(int), stream);
    hist_kernel<<<NE / 256, 256, 0, stream>>>(dstI, cnt);
    scan1<<<NSCANB, 256, 0, stream>>>(cnt, S1, bsum);
    scan2<<<1, 512, 0, stream>>>(bsum, boff);
    scan3<<<NSCANB, 256, 0, stream>>>(S1, boff, cnt, row_start, cursor);

    // ---- MEGA: edge GEMM (both layers) + node GEMM L1 + CSR scatter, co-scheduled ----
    mega_l1<<<EGRID + NGRID4 + SGRID, 256, 0, stream>>>(
        ea, WmT1, WmT2, EE1, EE2,
        x, WT1, bias1, Q, KV, H,
        srcI, dstI, cursor, csr_pair);

    attn_node<<<4096, 256, 0, stream>>>(Q, KV, EE1, row_start, csr_pair, H, H);

    // ---- layer 2 ----
    node_mfma<<<NGRID4, 256, 0, stream>>>(H, OUTF, OUTF, 1, NN, WT2, bias2, Q, KV, (float*)d_out);
    attn_node<<<4096, 256, 0, stream>>>(Q, KV, EE2, row_start, csr_pair, (float*)d_out, (float*)d_out);
}